// Round 6
// baseline (854.215 us; speedup 1.0000x reference)
//
#include <hip/hip_runtime.h>

// LSTM_1030792151143: 2-layer LSTM (B=2048, T=1000, F=40, H1=8, H2=6) + tanh + FC + sigmoid.
//
// Round 8: layer-split consumers (L1 wave + L2 wave, pipelined by one tile).
//   r5 measured 413us = 992 cy/step. Consumer wave issue audit: ~110 VALU x2cy +
//   22 TRANS x8cy (quarter-rate exp/rcp) + 23 DS + 2 exposed swizzle round-trips
//   ~= 900+ cy -> ONE in-order wave cannot run both layers faster. Split:
//     w0 = L1 recurrence only: dots+acts+c1+h1 bcast (8 swizzles); th1v written to
//          s_t1 via one per-lane ds_write_b32 (no th1 broadcast needed at all).
//     w1 = L2 recurrence, ONE TILE BEHIND: reads th1 rows from s_t1 via 2 prefetched
//          ds_read_b128 (8-addr/8-lane broadcast, 2-way bank max), h2 bcast 6 swizzles.
//     w2,w3 = producers (r7 verified code, restriped 2-way: 13 chunks, 10 rows each).
//   Handshake = existing per-phase barrier; L1 writes s_t1[(p-2)&1] while L2 reads
//   s_t1[(p-3)&1] -> disjoint parity, no race. TRANS per wave 22 -> ~11.
//   Math identical op-for-op (same accumulation order; th1 passes exact fp32 bits).

constexpr int Bn = 2048, Tn = 1000, Fn = 40;
constexpr int H1n = 8, H2n = 6;
constexpr int TT  = 20;                 // rows per tile (50 * 20 = 1000, no tail)
constexpr int NTt = Tn / TT;            // 50 tiles
constexpr int BW  = 8;                  // batches per block

constexpr int SROWF  = TT * Fn + 4;     // 804 floats per batch in s_x (16B pad)
constexpr int SXF    = BW * SROWF;      // 6432 floats per parity buffer
constexpr int SXB    = SXF * 4;         // 25728 bytes
constexpr int NCHUNK = (SXB + 1023) / 1024;   // 26 staging chunks of 64 lanes x 16B

__device__ __forceinline__ float frcp(float x) { return __builtin_amdgcn_rcpf(x); }
__device__ __forceinline__ float fsig(float x) { return frcp(1.0f + __expf(-x)); }
__device__ __forceinline__ float ftanh(float x) {
    return fmaf(2.0f, frcp(1.0f + __expf(-2.0f * x)), -1.0f);
}

// broadcast lane ((lane & 0x18) | K) within each 32-lane half: groups of 8 lanes.
template <int K>
__device__ __forceinline__ float bswz(float v) {
    return __int_as_float(__builtin_amdgcn_ds_swizzle(__float_as_int(v), (K << 5) | 0x18));
}

__global__ __launch_bounds__(256, 1) void lstm_upl(
    const float* __restrict__ x,
    const float* __restrict__ W_ih1, const float* __restrict__ W_hh1,
    const float* __restrict__ b_ih1, const float* __restrict__ b_hh1,
    const float* __restrict__ W_ih2, const float* __restrict__ W_hh2,
    const float* __restrict__ b_ih2, const float* __restrict__ b_hh2,
    const float* __restrict__ W_fc,  const float* __restrict__ b_fc,
    float* __restrict__ out)
{
    __shared__ float s_x [2][SXF];               // 51456 B (padded x tiles)
    __shared__ float s_xg[2][TT * BW * 32];      // 40960 B ([t][q][j][gate])
    __shared__ float s_t1[2][TT * BW * H1n];     // 10240 B ([t][q][j] = tanh(h1))

    const int lane  = threadIdx.x & 63;
    const int wslot = __builtin_amdgcn_readfirstlane((int)(threadIdx.x >> 6));
    const int b0    = blockIdx.x * BW;

    // Schedule (53 phases, p = 0..52):
    //   producers: stage x tile p -> s_x[p&1]                      (p < 50)
    //              xg tile p-1: s_x[(p-1)&1] -> s_xg[(p-1)&1]      (1 <= p <= 50)
    //   L1 wave  : tile p-2 from s_xg[(p-2)&1] -> th1 to s_t1[(p-2)&1]  (2 <= p <= 51)
    //   L2 wave  : tile p-3 from s_t1[(p-3)&1]                     (3 <= p <= 52)

    if (wslot == 0) {
        // ---------------- L1 wave: 8 batches, unit-per-lane ----------------
        const int q = lane >> 3;                  // batch in block
        const int j = lane & 7;                   // L1 hidden unit

        float wi1[H1n], wf1[H1n], wg1[H1n], wo1[H1n];
#pragma unroll
        for (int k = 0; k < H1n; ++k) {
            wi1[k] = W_hh1[(     j) * H1n + k];
            wf1[k] = W_hh1[( 8 + j) * H1n + k];
            wg1[k] = W_hh1[(16 + j) * H1n + k];
            wo1[k] = W_hh1[(24 + j) * H1n + k];
        }

        float c1 = 0.f;
        float h1s[H1n];
#pragma unroll
        for (int k = 0; k < H1n; ++k) h1s[k] = 0.f;

        const int myoff = q * 32 + j * 4;         // float offset of this lane's 4 gates

        for (int p = 0; p <= NTt + 2; ++p) {
            if (p >= 2 && p <= NTt + 1) {
                const int tile = p - 2;
                const float* xgt = &s_xg[tile & 1][0];
                float*       t1o = &s_t1[tile & 1][0];
                float4 xg4 = *(const float4*)(xgt + myoff);          // row 0 (sync)
                for (int i = 0; i < TT; ++i) {
                    const int in = (i + 1 < TT) ? (i + 1) : i;
                    const float4 xgn = *(const float4*)(xgt + in * (BW * 32) + myoff);

                    float ai0 = xg4.x, ai1 = 0.f, af0 = xg4.y, af1 = 0.f;
                    float ag0 = xg4.z, ag1 = 0.f, ao0 = xg4.w, ao1 = 0.f;
#pragma unroll
                    for (int k = 0; k < H1n; k += 2) {
                        ai0 = fmaf(h1s[k], wi1[k], ai0); ai1 = fmaf(h1s[k+1], wi1[k+1], ai1);
                        af0 = fmaf(h1s[k], wf1[k], af0); af1 = fmaf(h1s[k+1], wf1[k+1], af1);
                        ag0 = fmaf(h1s[k], wg1[k], ag0); ag1 = fmaf(h1s[k+1], wg1[k+1], ag1);
                        ao0 = fmaf(h1s[k], wo1[k], ao0); ao1 = fmaf(h1s[k+1], wo1[k+1], ao1);
                    }
                    const float iv = fsig (ai0 + ai1);
                    const float fv = fsig (af0 + af1);
                    const float gv = ftanh(ag0 + ag1);
                    const float ov = fsig (ao0 + ao1);
                    c1 = fmaf(fv, c1, iv * gv);
                    const float h1v = ov * ftanh(c1);

                    // broadcast h1 within the 8-lane group (only cross-lane L1 needs)
                    h1s[0] = bswz<0>(h1v); h1s[1] = bswz<1>(h1v);
                    h1s[2] = bswz<2>(h1v); h1s[3] = bswz<3>(h1v);
                    h1s[4] = bswz<4>(h1v); h1s[5] = bswz<5>(h1v);
                    h1s[6] = bswz<6>(h1v); h1s[7] = bswz<7>(h1v);

                    // th1 handoff: one per-lane scalar write (off-chain)
                    t1o[i * (BW * H1n) + q * H1n + j] = ftanh(h1v);

                    xg4 = xgn;
                }
            }
            __syncthreads();
        }
    } else if (wslot == 1) {
        // ---------------- L2 wave: one tile behind ----------------
        const int q  = lane >> 3;
        const int j  = lane & 7;
        const int j2 = (j < H2n) ? j : (H2n - 1);  // lanes 6,7 duplicate unit 5

        float wi2[H1n], wf2[H1n], wg2[H1n], wo2[H1n];
#pragma unroll
        for (int k = 0; k < H1n; ++k) {
            wi2[k] = W_ih2[(     j2) * H1n + k];
            wf2[k] = W_ih2[( 6 + j2) * H1n + k];
            wg2[k] = W_ih2[(12 + j2) * H1n + k];
            wo2[k] = W_ih2[(18 + j2) * H1n + k];
        }
        float vi2[H2n], vf2[H2n], vg2[H2n], vo2[H2n];
#pragma unroll
        for (int k = 0; k < H2n; ++k) {
            vi2[k] = W_hh2[(     j2) * H2n + k];
            vf2[k] = W_hh2[( 6 + j2) * H2n + k];
            vg2[k] = W_hh2[(12 + j2) * H2n + k];
            vo2[k] = W_hh2[(18 + j2) * H2n + k];
        }
        const float bi2c = b_ih2[     j2] + b_hh2[     j2];
        const float bf2c = b_ih2[ 6 + j2] + b_hh2[ 6 + j2];
        const float bg2c = b_ih2[12 + j2] + b_hh2[12 + j2];
        const float bo2c = b_ih2[18 + j2] + b_hh2[18 + j2];

        float wfc[H2n];
#pragma unroll
        for (int k = 0; k < H2n; ++k) wfc[k] = W_fc[k];
        const float bfc = b_fc[0];

        float c2 = 0.f;
        float h2s[H2n];
#pragma unroll
        for (int k = 0; k < H2n; ++k) h2s[k] = 0.f;

        const int tbase = q * H1n;                // th1 row offset for batch q

        for (int p = 0; p <= NTt + 2; ++p) {
            if (p >= 3) {
                const int tile = p - 3;
                const float* t1 = &s_t1[tile & 1][0];
                float4 ta = *(const float4*)(t1 + tbase);            // row 0 (sync)
                float4 tb = *(const float4*)(t1 + tbase + 4);
                for (int i = 0; i < TT; ++i) {
                    const int in = (i + 1 < TT) ? (i + 1) : i;
                    const float4 na = *(const float4*)(t1 + in * (BW * H1n) + tbase);
                    const float4 nb = *(const float4*)(t1 + in * (BW * H1n) + tbase + 4);

                    const float th1s[H1n] = { ta.x, ta.y, ta.z, ta.w,
                                              tb.x, tb.y, tb.z, tb.w };

                    // h2s-partials first (same accumulation order as verified r5/r7)
                    float bi0 = bi2c, bi1 = 0.f, bf0 = bf2c, bf1 = 0.f;
                    float bg0 = bg2c, bg1 = 0.f, bo0 = bo2c, bo1 = 0.f;
#pragma unroll
                    for (int k = 0; k < H2n; k += 2) {
                        bi0 = fmaf(h2s[k], vi2[k], bi0); bi1 = fmaf(h2s[k+1], vi2[k+1], bi1);
                        bf0 = fmaf(h2s[k], vf2[k], bf0); bf1 = fmaf(h2s[k+1], vf2[k+1], bf1);
                        bg0 = fmaf(h2s[k], vg2[k], bg0); bg1 = fmaf(h2s[k+1], vg2[k+1], bg1);
                        bo0 = fmaf(h2s[k], vo2[k], bo0); bo1 = fmaf(h2s[k+1], vo2[k+1], bo1);
                    }
#pragma unroll
                    for (int k = 0; k < H1n; k += 2) {
                        bi0 = fmaf(th1s[k], wi2[k], bi0); bi1 = fmaf(th1s[k+1], wi2[k+1], bi1);
                        bf0 = fmaf(th1s[k], wf2[k], bf0); bf1 = fmaf(th1s[k+1], wf2[k+1], bf1);
                        bg0 = fmaf(th1s[k], wg2[k], bg0); bg1 = fmaf(th1s[k+1], wg2[k+1], bg1);
                        bo0 = fmaf(th1s[k], wo2[k], bo0); bo1 = fmaf(th1s[k+1], wo2[k+1], bo1);
                    }
                    const float i2v = fsig (bi0 + bi1);
                    const float f2v = fsig (bf0 + bf1);
                    const float g2v = ftanh(bg0 + bg1);
                    const float o2v = fsig (bo0 + bo1);
                    c2 = fmaf(f2v, c2, i2v * g2v);
                    const float h2v = o2v * ftanh(c2);

                    h2s[0] = bswz<0>(h2v); h2s[1] = bswz<1>(h2v);
                    h2s[2] = bswz<2>(h2v); h2s[3] = bswz<3>(h2v);
                    h2s[4] = bswz<4>(h2v); h2s[5] = bswz<5>(h2v);

                    ta = na; tb = nb;
                }
            }
            __syncthreads();
        }

        if (j == 0) {                              // lanes 0,8,...,56 -> out[b0 + q]
            float a = bfc;
#pragma unroll
            for (int k = 0; k < H2n; ++k) a = fmaf(ftanh(h2s[k]), wfc[k], a);
            out[b0 + q] = fsig(a);
        }
    } else {
        // ---------------- producers: lane = (batch q, unit j), 4 gates/lane ----------
        const int wp = wslot - 2;                  // 0..1 (stripe)
        const int q  = lane >> 3;                  // batch
        const int j  = lane & 7;                   // L1 unit

        float wI[Fn], wF[Fn], wG[Fn], wO[Fn];      // W_ih1 rows j, 8+j, 16+j, 24+j
#pragma unroll
        for (int k = 0; k < Fn; ++k) {
            wI[k] = W_ih1[(     j) * Fn + k];
            wF[k] = W_ih1[( 8 + j) * Fn + k];
            wG[k] = W_ih1[(16 + j) * Fn + k];
            wO[k] = W_ih1[(24 + j) * Fn + k];
        }
        const float bI = b_ih1[     j] + b_hh1[     j];
        const float bF = b_ih1[ 8 + j] + b_hh1[ 8 + j];
        const float bG = b_ih1[16 + j] + b_hh1[16 + j];
        const float bO = b_ih1[24 + j] + b_hh1[24 + j];

        const char* xcb = (const char*)x;

        for (int p = 0; p <= NTt + 2; ++p) {
            // 1) issue stage loads for tile p (kept in regs; LDS-written after compute)
            float4 vv[13];
            if (p < NTt) {
#pragma unroll
                for (int ci = 0; ci < 13; ++ci) {
                    const int c = wp + ci * 2;
                    if (c < NCHUNK) {
                        const int o = c * 1024 + lane * 16;     // byte offset in s_x buffer
                        if (o < SXB) {
                            const int qq  = o / (SROWF * 4);    // batch (3216 B stride)
                            int       rem = o - qq * (SROWF * 4);
                            if (rem > TT * Fn * 4 - 16) rem = TT * Fn * 4 - 16;  // pad clamp
                            vv[ci] = *(const float4*)(xcb
                                       + (size_t)(b0 + qq) * (Tn * Fn * 4)
                                       + (size_t)p * (TT * Fn * 4) + rem);
                        }
                    }
                }
            }

            // 2) xg for tile p-1: 8-way-divergent b128 reads, one b128 write per row
            if (p >= 1 && p <= NTt) {
                const float* xq = &s_x[(p - 1) & 1][0] + q * SROWF;
                float*       so = &s_xg[(p - 1) & 1][0];
                for (int r = wp; r < TT; r += 2) {
                    const float* xr = xq + r * Fn;
                    float i0 = bI, i1 = 0.f, i2 = 0.f, i3 = 0.f;
                    float f0 = bF, f1 = 0.f, f2 = 0.f, f3 = 0.f;
                    float g0 = bG, g1 = 0.f, g2 = 0.f, g3 = 0.f;
                    float o0 = bO, o1 = 0.f, o2 = 0.f, o3 = 0.f;
#pragma unroll
                    for (int k = 0; k < Fn; k += 4) {
                        const float4 cv = *(const float4*)&xr[k];
                        i0 = fmaf(cv.x, wI[k],     i0); i1 = fmaf(cv.y, wI[k + 1], i1);
                        i2 = fmaf(cv.z, wI[k + 2], i2); i3 = fmaf(cv.w, wI[k + 3], i3);
                        f0 = fmaf(cv.x, wF[k],     f0); f1 = fmaf(cv.y, wF[k + 1], f1);
                        f2 = fmaf(cv.z, wF[k + 2], f2); f3 = fmaf(cv.w, wF[k + 3], f3);
                        g0 = fmaf(cv.x, wG[k],     g0); g1 = fmaf(cv.y, wG[k + 1], g1);
                        g2 = fmaf(cv.z, wG[k + 2], g2); g3 = fmaf(cv.w, wG[k + 3], g3);
                        o0 = fmaf(cv.x, wO[k],     o0); o1 = fmaf(cv.y, wO[k + 1], o1);
                        o2 = fmaf(cv.z, wO[k + 2], o2); o3 = fmaf(cv.w, wO[k + 3], o3);
                    }
                    float4 r4;
                    r4.x = (i0 + i1) + (i2 + i3);
                    r4.y = (f0 + f1) + (f2 + f3);
                    r4.z = (g0 + g1) + (g2 + g3);
                    r4.w = (o0 + o1) + (o2 + o3);
                    *(float4*)&so[(r * BW + q) * 32 + j * 4] = r4;
                }
            }

            // 3) LDS-write the staged tile (vmcnt wait lands here, hidden under step 2)
            if (p < NTt) {
                char* ld = (char*)&s_x[p & 1][0];
#pragma unroll
                for (int ci = 0; ci < 13; ++ci) {
                    const int c = wp + ci * 2;
                    if (c < NCHUNK) {
                        const int o = c * 1024 + lane * 16;
                        if (o < SXB) *(float4*)(ld + o) = vv[ci];
                    }
                }
            }
            __syncthreads();
        }
    }
}

extern "C" void kernel_launch(void* const* d_in, const int* in_sizes, int n_in,
                              void* d_out, int out_size, void* d_ws, size_t ws_size,
                              hipStream_t stream) {
    (void)in_sizes; (void)n_in; (void)out_size; (void)d_ws; (void)ws_size;
    const float* x     = (const float*)d_in[0];
    const float* W_ih1 = (const float*)d_in[1];
    const float* W_hh1 = (const float*)d_in[2];
    const float* b_ih1 = (const float*)d_in[3];
    const float* b_hh1 = (const float*)d_in[4];
    const float* W_ih2 = (const float*)d_in[5];
    const float* W_hh2 = (const float*)d_in[6];
    const float* b_ih2 = (const float*)d_in[7];
    const float* b_hh2 = (const float*)d_in[8];
    const float* W_fc  = (const float*)d_in[9];
    const float* b_fc  = (const float*)d_in[10];
    float* out = (float*)d_out;

    lstm_upl<<<dim3(Bn / BW), dim3(256), 0, stream>>>(x, W_ih1, W_hh1, b_ih1, b_hh1,
                                                      W_ih2, W_hh2, b_ih2, b_hh2,
                                                      W_fc, b_fc, out);
}